// Round 2
// baseline (129421.729 us; speedup 1.0000x reference)
//
#include <hip/hip_runtime.h>
#include <cstdint>
#include <cstddef>

// ---------------------------------------------------------------------------
// Trainer_91216515433187: BN + Dense + LSTM encoder (1024 steps) + 35-step
// autoregressive LSTM decoder.
//
// Round 2: round-1's agent acquire/release fences (buffer_wbl2 + buffer_inv
// every step AND every poll iteration) were the 8000-cyc/step bottleneck
// (WRITE_SIZE 137 MB = h exchange going to HBM). Replaced with RELAXED
// agent-scope atomics (sc1: bypass L1/L2, serviced at the IC coherence
// point) for both h data and flags -> zero cache-maintenance instructions.
// Ordering: __syncthreads() drains vmcnt(0) per wave before s_barrier, so
// all sc1 h-stores are ack'd at the coherence point before tid0 publishes
// the flag (this is LLVM's agent-release mapping minus wbl2, which only
// protects cached accesses we no longer make). The LOCAL 128 cols of h now
// go through LDS; only the partner's 128 cols cross memory. Remote loads
// are issued before local/pulse MFMAs so IC latency overlaps compute.
// ---------------------------------------------------------------------------

typedef _Float16 h8 __attribute__((ext_vector_type(8)));
typedef float f4 __attribute__((ext_vector_type(4)));
typedef unsigned long long u64x2 __attribute__((ext_vector_type(2)));

// ws byte offsets
#define WS_FLAGS  0         // 32 slots x 64 B = 2048
#define WS_HBUF   2048      // 2 par x 16 tiles x 16 rows x 256 k f16 = 262144
#define WS_RKT    264192    // 1024 cols x 256 k f16 = 524288
#define WS_WEFF   788480    // 1024 cols x 8 f f16 = 16384
#define WS_WMLP   804864    // 2 e x 256 k f16 = 1024
#define WS_DEFF   805888    // 2 x 1024 f32 = 8192
#define WS_ZB     814080    // 1024 f32
#define WS_DB     818176    // 1024 f32
#define WS_TOTAL  822272

__device__ __forceinline__ float fexp2(float x){
#if __has_builtin(__builtin_amdgcn_exp2f)
  return __builtin_amdgcn_exp2f(x);
#else
  return exp2f(x);
#endif
}
__device__ __forceinline__ float frcp(float x){
#if __has_builtin(__builtin_amdgcn_rcpf)
  return __builtin_amdgcn_rcpf(x);
#else
  return 1.f / x;
#endif
}
__device__ __forceinline__ float sigf(float x){
  return frcp(1.f + fexp2(-1.44269504f * x));
}
__device__ __forceinline__ float tanh_f(float x){
  return 2.f * frcp(1.f + fexp2(-2.88539008f * x)) - 1.f;
}

__global__ void zero_ws_k(uint32_t* __restrict__ p, int n){
  int i = blockIdx.x * 256 + threadIdx.x;
  if (i < n) p[i] = 0u;
}

// grid 1024 x 256 threads
__global__ void precompute_k(const float* __restrict__ bn_gamma,
                             const float* __restrict__ bn_beta,
                             const float* __restrict__ bn_mean,
                             const float* __restrict__ bn_var,
                             const float* __restrict__ W_pulse,   // (8,256)
                             const float* __restrict__ b_pulse,   // (256)
                             const float* __restrict__ lstm_k,    // (256,1024)
                             const float* __restrict__ lstm_rk,   // (256,1024)
                             const float* __restrict__ lstm_b,    // (1024)
                             const float* __restrict__ W_eis,     // (2,256)
                             const float* __restrict__ b_eis,     // (256)
                             const float* __restrict__ W_mlp,     // (256,2)
                             _Float16* __restrict__ rkT,          // [col][k]
                             _Float16* __restrict__ WeffT,        // [col][f]
                             _Float16* __restrict__ WmlpT,        // [e][k]
                             float* __restrict__ Deff,            // [e][col]
                             float* __restrict__ zbias,
                             float* __restrict__ dbias)
{
  int gid = blockIdx.x * 256 + threadIdx.x;   // 0..262143
  {
    int col = gid >> 8;
    int k   = gid & 255;
    rkT[col * 256 + k] = (_Float16)lstm_rk[k * 1024 + col];
  }
  if (gid < 512) {
    int e = gid >> 8, k = gid & 255;
    WmlpT[e * 256 + k] = (_Float16)W_mlp[k * 2 + e];
  }
  if (gid < 1024) {
    int j = gid;
    float a[8], bv[8];
#pragma unroll
    for (int f = 0; f < 8; ++f) {
      float af = bn_gamma[f] * rsqrtf(bn_var[f] + 1e-3f);
      a[f]  = af;
      bv[f] = bn_beta[f] - bn_mean[f] * af;
    }
    float m[8] = {0,0,0,0,0,0,0,0};
    float d0 = 0.f, d1 = 0.f, zb2 = 0.f, db2 = 0.f;
    for (int k = 0; k < 256; ++k) {
      float lk = lstm_k[k * 1024 + j];
#pragma unroll
      for (int f = 0; f < 8; ++f) m[f] += W_pulse[f * 256 + k] * lk;
      d0  += W_eis[k]       * lk;
      d1  += W_eis[256 + k] * lk;
      zb2 += b_pulse[k] * lk;
      db2 += b_eis[k]   * lk;
    }
    float zb = lstm_b[j] + zb2;
#pragma unroll
    for (int f = 0; f < 8; ++f) {
      zb += bv[f] * m[f];
      WeffT[j * 8 + f] = (_Float16)(a[f] * m[f]);
    }
    zbias[j] = zb;
    dbias[j] = lstm_b[j] + db2;
    Deff[j]        = d0;
    Deff[1024 + j] = d1;
  }
}

// 32 blocks x 512 threads
__global__ __launch_bounds__(512, 2)
void lstm_main_k(const float* __restrict__ pulse,      // (256,1024,8)
                 const float* __restrict__ embed,      // (1,2)
                 const float* __restrict__ b_mlp,      // (2)
                 const float* __restrict__ scale_w,    // (2)
                 const float* __restrict__ scale_b,    // (2)
                 const _Float16* __restrict__ rkT,
                 const _Float16* __restrict__ WeffT,
                 const _Float16* __restrict__ WmlpT,
                 const float* __restrict__ Deff,
                 const float* __restrict__ zbias,
                 const float* __restrict__ dbias,
                 _Float16* __restrict__ hbuf,          // [par][tile][row][k]
                 int* __restrict__ flags,              // [32 slots x 16 ints]
                 float* __restrict__ out)              // (256,35,2)
{
  const int tid  = threadIdx.x;
  const int wave = tid >> 6;
  const int lane = tid & 63;
  const int quad = lane >> 4;
  const int n    = lane & 15;

  const int bid     = blockIdx.x;
  const int tile    = bid & 15;
  const int half_id = bid >> 4;
  const int b0      = tile * 16;
  const int hc0     = half_id * 128 + wave * 16;
  const int col_h   = hc0 + n;
  const int col_loc = wave * 16 + n;                  // local col within half

  const int slot  = tile * 2 + half_id;
  const int pslot = tile * 2 + (half_id ^ 1);

  __shared__ _Float16 wm_lds[8 * 64 * 8];             // W_mlp B-frags
  __shared__ float    tok_lds[32];                    // [row][e]
  __shared__ __align__(16) _Float16 hl[2][16 * 136];  // local h: [par][row][128+8pad]

  // Build W_mlp fragment LDS (N padded 2->16 with zeros).
  {
    int s8 = tid >> 6, L = tid & 63;
    int nn = L & 15, kq = L >> 4;
    h8 v;
#pragma unroll
    for (int j = 0; j < 8; ++j) {
      int k = s8 * 32 + kq * 8 + j;
      v[j] = (nn < 2) ? WmlpT[nn * 256 + k] : (_Float16)0.f;
    }
    *reinterpret_cast<h8*>(&wm_lds[(s8 * 64 + L) * 8]) = v;
  }
  // Zero local-h LDS (h_0 = 0).
  for (int i = tid; i < 2 * 16 * 136; i += 512) hl[0][i] = (_Float16)0.f;

  // Register-resident weight fragments.
  h8 W[4][8];
  h8 Wf[4];
  float zb[4], db[4], D0[4], D1[4];
#pragma unroll
  for (int g = 0; g < 4; ++g) {
    int col = g * 256 + col_h;
    const _Float16* wp = rkT + col * 256 + quad * 8;
#pragma unroll
    for (int s8 = 0; s8 < 8; ++s8)
      W[g][s8] = *reinterpret_cast<const h8*>(wp + s8 * 32);
    if (quad == 0) {
      Wf[g] = *reinterpret_cast<const h8*>(WeffT + col * 8);
    } else {
#pragma unroll
      for (int j = 0; j < 8; ++j) Wf[g][j] = (_Float16)0.f;
    }
    zb[g] = zbias[col];
    db[g] = dbias[col];
    D0[g] = Deff[col];
    D1[g] = Deff[1024 + col];
  }
  const float sw  = (n < 2) ? scale_w[n] : 0.f;
  const float sb_ = (n < 2) ? scale_b[n] : 0.f;
  const float bm  = (n < 2) ? b_mlp[n]   : 0.f;

  f4 c_frag = {0.f, 0.f, 0.f, 0.f};

  __syncthreads();

  const int rhalf = half_id ^ 1;
  // remote A-frag base: row = n, k = rhalf*128 + quad*8
  const int hrow_rd_rem = (tile * 16 + n) * 256 + rhalf * 128 + quad * 8;
  // store base (row = quad*4 + r, col = col_h)
  const int hrow_wr = (tile * 16 + quad * 4) * 256 + col_h;
  const float* prow = pulse + (size_t)(b0 + n) * 1024 * 8;

  const int lloc = half_id * 4;  // ha index base for local frags
  const int lrem = rhalf * 4;    // ha index base for remote frags

#define LOAD_REMOTE(ha, parR)                                                 \
  {                                                                           \
    const unsigned long long* rp = (const unsigned long long*)                \
        (hbuf + (parR) * 65536 + hrow_rd_rem);                                \
    unsigned long long r0[4], r1[4];                                          \
    _Pragma("unroll")                                                         \
    for (int s = 0; s < 4; ++s) {                                             \
      r0[s] = __hip_atomic_load(rp + s * 8,     __ATOMIC_RELAXED,             \
                                __HIP_MEMORY_SCOPE_AGENT);                    \
      r1[s] = __hip_atomic_load(rp + s * 8 + 1, __ATOMIC_RELAXED,             \
                                __HIP_MEMORY_SCOPE_AGENT);                    \
    }                                                                         \
    _Pragma("unroll")                                                         \
    for (int s = 0; s < 4; ++s) {                                             \
      u64x2 t2; t2[0] = r0[s]; t2[1] = r1[s];                                 \
      ha[lrem + s] = __builtin_bit_cast(h8, t2);                              \
    }                                                                         \
  }

#define LOAD_LOCAL(ha, parR)                                                  \
  {                                                                           \
    _Pragma("unroll")                                                         \
    for (int s = 0; s < 4; ++s)                                               \
      ha[lloc + s] = *reinterpret_cast<const h8*>(                            \
          &hl[parR][n * 136 + quad * 8 + s * 32]);                            \
  }

#define STORE_H(parW, hv, r)                                                  \
  {                                                                           \
    hl[parW][(quad * 4 + (r)) * 136 + col_loc] = (hv);                        \
    __hip_atomic_store((unsigned short*)(hbuf + (parW) * 65536 + hrow_wr +    \
                                         (r) * 256),                          \
                       __builtin_bit_cast(unsigned short, (hv)),              \
                       __ATOMIC_RELAXED, __HIP_MEMORY_SCOPE_AGENT);           \
  }

#define SYNC_STEP(t)                                                          \
  {                                                                           \
    __syncthreads(); /* drains vmcnt(0): all sc1 h-stores ack'd at IC */      \
    if (tid == 0) {                                                           \
      __hip_atomic_store(flags + slot * 16, (t) + 1, __ATOMIC_RELAXED,        \
                         __HIP_MEMORY_SCOPE_AGENT);                           \
      while (__hip_atomic_load(flags + pslot * 16, __ATOMIC_RELAXED,          \
                               __HIP_MEMORY_SCOPE_AGENT) < (t) + 1) { }       \
    }                                                                         \
    __syncthreads();                                                          \
  }

  // ---------------- encoder: t = 0..1023 ----------------
  for (int t = 0; t < 1024; ++t) {
    const int parR = t & 1;
    const int parW = parR ^ 1;

    h8 ha[8];
    LOAD_REMOTE(ha, parR)     // issue IC loads first (latency overlap)
    LOAD_LOCAL(ha, parR)

    h8 pa;
#pragma unroll
    for (int j = 0; j < 8; ++j) pa[j] = (_Float16)0.f;
    if (quad == 0) {
      const f4* pp = reinterpret_cast<const f4*>(prow + (size_t)t * 8);
      f4 p0 = pp[0], p1 = pp[1];
      pa[0] = (_Float16)p0[0]; pa[1] = (_Float16)p0[1];
      pa[2] = (_Float16)p0[2]; pa[3] = (_Float16)p0[3];
      pa[4] = (_Float16)p1[0]; pa[5] = (_Float16)p1[1];
      pa[6] = (_Float16)p1[2]; pa[7] = (_Float16)p1[3];
    }

    f4 acc[4];
#pragma unroll
    for (int g = 0; g < 4; ++g) {
      acc[g][0] = zb[g]; acc[g][1] = zb[g]; acc[g][2] = zb[g]; acc[g][3] = zb[g];
      acc[g] = __builtin_amdgcn_mfma_f32_16x16x32_f16(pa, Wf[g], acc[g], 0, 0, 0);
    }
    // local-half MFMAs first (LDS data, ready early)
#pragma unroll
    for (int s = 0; s < 4; ++s) {
#pragma unroll
      for (int g = 0; g < 4; ++g)
        acc[g] = __builtin_amdgcn_mfma_f32_16x16x32_f16(ha[lloc + s], W[g][lloc + s], acc[g], 0, 0, 0);
    }
    // remote-half MFMAs (IC loads have had time to land)
#pragma unroll
    for (int s = 0; s < 4; ++s) {
#pragma unroll
      for (int g = 0; g < 4; ++g)
        acc[g] = __builtin_amdgcn_mfma_f32_16x16x32_f16(ha[lrem + s], W[g][lrem + s], acc[g], 0, 0, 0);
    }

#pragma unroll
    for (int r = 0; r < 4; ++r) {
      float iv = sigf(acc[0][r]);
      float fv = sigf(acc[1][r]);
      float gv = tanh_f(acc[2][r]);
      float ov = sigf(acc[3][r]);
      float cc = fv * c_frag[r] + iv * gv;
      c_frag[r] = cc;
      _Float16 hv = (_Float16)(ov * tanh_f(cc));
      STORE_H(parW, hv, r)
    }

    SYNC_STEP(t)
  }

  // ---------------- decoder: 35 steps ----------------
  if (tid < 32) tok_lds[tid] = embed[tid & 1];
  __syncthreads();

  for (int s = 0; s < 35; ++s) {
    const int t = 1024 + s;
    const int parR = t & 1;
    const int parW = parR ^ 1;

    h8 ha[8];
    LOAD_REMOTE(ha, parR)
    LOAD_LOCAL(ha, parR)

    if (s > 0) {
      // pred_{s-1} = h_t @ W_mlp + b_mlp  (wave0 publishes)
      f4 pf; pf[0] = bm; pf[1] = bm; pf[2] = bm; pf[3] = bm;
#pragma unroll
      for (int s8 = 0; s8 < 8; ++s8) {
        h8 wb = *reinterpret_cast<const h8*>(&wm_lds[(s8 * 64 + lane) * 8]);
        pf = __builtin_amdgcn_mfma_f32_16x16x32_f16(ha[s8], wb, pf, 0, 0, 0);
      }
      if (wave == 0 && n < 2) {
#pragma unroll
        for (int r = 0; r < 4; ++r) {
          int row = quad * 4 + r;
          float v = pf[r];
          tok_lds[row * 2 + n] = v;
          if (half_id == 0)
            out[((b0 + row) * 35 + (s - 1)) * 2 + n] = v * sw + sb_;
        }
      }
      __syncthreads();
    }

    float tk0[4], tk1[4];
#pragma unroll
    for (int r = 0; r < 4; ++r) {
      int row = quad * 4 + r;
      tk0[r] = tok_lds[row * 2];
      tk1[r] = tok_lds[row * 2 + 1];
    }
    f4 acc[4];
#pragma unroll
    for (int g = 0; g < 4; ++g) {
#pragma unroll
      for (int r = 0; r < 4; ++r)
        acc[g][r] = db[g] + tk0[r] * D0[g] + tk1[r] * D1[g];
    }
#pragma unroll
    for (int s8 = 0; s8 < 8; ++s8) {
#pragma unroll
      for (int g = 0; g < 4; ++g)
        acc[g] = __builtin_amdgcn_mfma_f32_16x16x32_f16(ha[s8], W[g][s8], acc[g], 0, 0, 0);
    }

#pragma unroll
    for (int r = 0; r < 4; ++r) {
      float iv = sigf(acc[0][r]);
      float fv = sigf(acc[1][r]);
      float gv = tanh_f(acc[2][r]);
      float ov = sigf(acc[3][r]);
      float cc = fv * c_frag[r] + iv * gv;
      c_frag[r] = cc;
      _Float16 hv = (_Float16)(ov * tanh_f(cc));
      STORE_H(parW, hv, r)
    }

    SYNC_STEP(t)
  }

  // final pred_34 from h_{1059} (parity 1)
  {
    h8 ha[8];
    LOAD_REMOTE(ha, 1)
    LOAD_LOCAL(ha, 1)
    f4 pf; pf[0] = bm; pf[1] = bm; pf[2] = bm; pf[3] = bm;
#pragma unroll
    for (int s8 = 0; s8 < 8; ++s8) {
      h8 wb = *reinterpret_cast<const h8*>(&wm_lds[(s8 * 64 + lane) * 8]);
      pf = __builtin_amdgcn_mfma_f32_16x16x32_f16(ha[s8], wb, pf, 0, 0, 0);
    }
    if (half_id == 0 && wave == 0 && n < 2) {
#pragma unroll
      for (int r = 0; r < 4; ++r) {
        int row = quad * 4 + r;
        out[((b0 + row) * 35 + 34) * 2 + n] = pf[r] * sw + sb_;
      }
    }
  }
#undef LOAD_REMOTE
#undef LOAD_LOCAL
#undef STORE_H
#undef SYNC_STEP
}

extern "C" void kernel_launch(void* const* d_in, const int* in_sizes, int n_in,
                              void* d_out, int out_size, void* d_ws, size_t ws_size,
                              hipStream_t stream) {
  const float* pulse    = (const float*)d_in[0];
  const float* bn_gamma = (const float*)d_in[1];
  const float* bn_beta  = (const float*)d_in[2];
  const float* bn_mean  = (const float*)d_in[3];
  const float* bn_var   = (const float*)d_in[4];
  const float* W_pulse  = (const float*)d_in[5];
  const float* b_pulse  = (const float*)d_in[6];
  const float* lstm_k   = (const float*)d_in[7];
  const float* lstm_rk  = (const float*)d_in[8];
  const float* lstm_b   = (const float*)d_in[9];
  const float* embed    = (const float*)d_in[10];
  const float* W_eis    = (const float*)d_in[11];
  const float* b_eis    = (const float*)d_in[12];
  const float* W_mlp    = (const float*)d_in[13];
  const float* b_mlp    = (const float*)d_in[14];
  const float* scale_w  = (const float*)d_in[15];
  const float* scale_b  = (const float*)d_in[16];

  char* ws = (char*)d_ws;
  int*      flags = (int*)(ws + WS_FLAGS);
  _Float16* hbuf  = (_Float16*)(ws + WS_HBUF);
  _Float16* rkT   = (_Float16*)(ws + WS_RKT);
  _Float16* WeffT = (_Float16*)(ws + WS_WEFF);
  _Float16* WmlpT = (_Float16*)(ws + WS_WMLP);
  float*    Deff  = (float*)(ws + WS_DEFF);
  float*    zbias = (float*)(ws + WS_ZB);
  float*    dbias = (float*)(ws + WS_DB);

  // zero flags + h double-buffer: (2048 + 262144)/4 = 66048 words
  zero_ws_k<<<258, 256, 0, stream>>>((uint32_t*)d_ws, 66048);
  precompute_k<<<1024, 256, 0, stream>>>(bn_gamma, bn_beta, bn_mean, bn_var,
                                         W_pulse, b_pulse, lstm_k, lstm_rk, lstm_b,
                                         W_eis, b_eis, W_mlp,
                                         rkT, WeffT, WmlpT, Deff, zbias, dbias);
  lstm_main_k<<<32, 512, 0, stream>>>(pulse, embed, b_mlp, scale_w, scale_b,
                                      rkT, WeffT, WmlpT, Deff, zbias, dbias,
                                      hbuf, flags, (float*)d_out);
}

// Round 3
// 10084.648 us; speedup vs baseline: 12.8335x; 12.8335x over previous
//
#include <hip/hip_runtime.h>
#include <cstdint>
#include <cstddef>

// ---------------------------------------------------------------------------
// Trainer_91216515433187: BN + Dense + LSTM encoder (1024 steps) + 35-step
// autoregressive LSTM decoder.
//
// Round 3: round-2 post-mortem showed relaxed agent atomics do NOT bypass the
// per-XCD L2 (visibility only on eviction -> 120us/step). This round keeps the
// round-1 topology (32 blocks = 16 tile-pairs, weights register-resident,
// monotone flag protocol) but does the h exchange with explicit inline-asm
// sc0 sc1 accesses (IC-coherent, no wbl2/buffer_inv):
//   * remote h:  global_load_dwordx4 ... sc0 sc1 (issued before local MFMAs,
//                explicit s_waitcnt tied to result regs before remote MFMAs)
//   * h publish: global_store_short ... sc0 sc1 (4 per lane, 32B segments)
//   * flags:     global_store_dword / global_load_dword ... sc0 sc1,
//                per-wave polling (single barrier per step)
//   * local h:   LDS, parity double-buffered (round-2's working piece)
// ---------------------------------------------------------------------------

typedef _Float16 h8 __attribute__((ext_vector_type(8)));
typedef float f4 __attribute__((ext_vector_type(4)));

// ws byte offsets
#define WS_FLAGS  0         // 32 slots x 64 B = 2048
#define WS_HBUF   2048      // 2 par x 16 tiles x 16 rows x 256 k f16 = 262144
#define WS_RKT    264192    // 1024 cols x 256 k f16 = 524288
#define WS_WEFF   788480    // 1024 cols x 8 f f16 = 16384
#define WS_WMLP   804864    // 2 e x 256 k f16 = 1024
#define WS_DEFF   805888    // 2 x 1024 f32 = 8192
#define WS_ZB     814080    // 1024 f32
#define WS_DB     818176    // 1024 f32
#define WS_TOTAL  822272

__device__ __forceinline__ float fexp2(float x){
#if __has_builtin(__builtin_amdgcn_exp2f)
  return __builtin_amdgcn_exp2f(x);
#else
  return exp2f(x);
#endif
}
__device__ __forceinline__ float frcp(float x){
#if __has_builtin(__builtin_amdgcn_rcpf)
  return __builtin_amdgcn_rcpf(x);
#else
  return 1.f / x;
#endif
}
__device__ __forceinline__ float sigf(float x){
  return frcp(1.f + fexp2(-1.44269504f * x));
}
__device__ __forceinline__ float tanh_f(float x){
  return 2.f * frcp(1.f + fexp2(-2.88539008f * x)) - 1.f;
}

// ---- IC-coherent (device-scope) access helpers: sc0 sc1 bypass L1+L2 ------
__device__ __forceinline__ h8 ic_load16(const _Float16* p){
  h8 r;
  asm volatile("global_load_dwordx4 %0, %1, off sc0 sc1" : "=v"(r) : "v"(p));
  return r;   // NOT ready until a subsequent s_waitcnt tied to r
}
__device__ __forceinline__ void ic_wait4(h8& a, h8& b, h8& c, h8& d){
  asm volatile("s_waitcnt vmcnt(0)"
               : "+v"(a), "+v"(b), "+v"(c), "+v"(d));
}
__device__ __forceinline__ void ic_store_h16(_Float16* p, unsigned int v){
  asm volatile("global_store_short %0, %1, off sc0 sc1"
               :: "v"(p), "v"(v) : "memory");
}
__device__ __forceinline__ void ic_fence_stores(){
  asm volatile("s_waitcnt vmcnt(0)" ::: "memory");
}
__device__ __forceinline__ void ic_store_flag(int* p, int v){
  asm volatile("global_store_dword %0, %1, off sc0 sc1"
               :: "v"(p), "v"(v) : "memory");
}
__device__ __forceinline__ int ic_load_flag(const int* p){
  int r;
  asm volatile("global_load_dword %0, %1, off sc0 sc1\n\ts_waitcnt vmcnt(0)"
               : "=v"(r) : "v"(p) : "memory");
  return r;
}

__global__ void zero_ws_k(uint32_t* __restrict__ p, int n){
  int i = blockIdx.x * 256 + threadIdx.x;
  if (i < n) p[i] = 0u;
}

// grid 1024 x 256 threads
__global__ void precompute_k(const float* __restrict__ bn_gamma,
                             const float* __restrict__ bn_beta,
                             const float* __restrict__ bn_mean,
                             const float* __restrict__ bn_var,
                             const float* __restrict__ W_pulse,   // (8,256)
                             const float* __restrict__ b_pulse,   // (256)
                             const float* __restrict__ lstm_k,    // (256,1024)
                             const float* __restrict__ lstm_rk,   // (256,1024)
                             const float* __restrict__ lstm_b,    // (1024)
                             const float* __restrict__ W_eis,     // (2,256)
                             const float* __restrict__ b_eis,     // (256)
                             const float* __restrict__ W_mlp,     // (256,2)
                             _Float16* __restrict__ rkT,          // [col][k]
                             _Float16* __restrict__ WeffT,        // [col][f]
                             _Float16* __restrict__ WmlpT,        // [e][k]
                             float* __restrict__ Deff,            // [e][col]
                             float* __restrict__ zbias,
                             float* __restrict__ dbias)
{
  int gid = blockIdx.x * 256 + threadIdx.x;   // 0..262143
  {
    int col = gid >> 8;
    int k   = gid & 255;
    rkT[col * 256 + k] = (_Float16)lstm_rk[k * 1024 + col];
  }
  if (gid < 512) {
    int e = gid >> 8, k = gid & 255;
    WmlpT[e * 256 + k] = (_Float16)W_mlp[k * 2 + e];
  }
  if (gid < 1024) {
    int j = gid;
    float a[8], bv[8];
#pragma unroll
    for (int f = 0; f < 8; ++f) {
      float af = bn_gamma[f] * rsqrtf(bn_var[f] + 1e-3f);
      a[f]  = af;
      bv[f] = bn_beta[f] - bn_mean[f] * af;
    }
    float m[8] = {0,0,0,0,0,0,0,0};
    float d0 = 0.f, d1 = 0.f, zb2 = 0.f, db2 = 0.f;
    for (int k = 0; k < 256; ++k) {
      float lk = lstm_k[k * 1024 + j];
#pragma unroll
      for (int f = 0; f < 8; ++f) m[f] += W_pulse[f * 256 + k] * lk;
      d0  += W_eis[k]       * lk;
      d1  += W_eis[256 + k] * lk;
      zb2 += b_pulse[k] * lk;
      db2 += b_eis[k]   * lk;
    }
    float zb = lstm_b[j] + zb2;
#pragma unroll
    for (int f = 0; f < 8; ++f) {
      zb += bv[f] * m[f];
      WeffT[j * 8 + f] = (_Float16)(a[f] * m[f]);
    }
    zbias[j] = zb;
    dbias[j] = lstm_b[j] + db2;
    Deff[j]        = d0;
    Deff[1024 + j] = d1;
  }
}

// 32 blocks x 512 threads
__global__ __launch_bounds__(512, 2)
void lstm_main_k(const float* __restrict__ pulse,      // (256,1024,8)
                 const float* __restrict__ embed,      // (1,2)
                 const float* __restrict__ b_mlp,      // (2)
                 const float* __restrict__ scale_w,    // (2)
                 const float* __restrict__ scale_b,    // (2)
                 const _Float16* __restrict__ rkT,
                 const _Float16* __restrict__ WeffT,
                 const _Float16* __restrict__ WmlpT,
                 const float* __restrict__ Deff,
                 const float* __restrict__ zbias,
                 const float* __restrict__ dbias,
                 _Float16* __restrict__ hbuf,          // [par][tile][row][k]
                 int* __restrict__ flags,              // [32 slots x 16 ints]
                 float* __restrict__ out)              // (256,35,2)
{
  const int tid  = threadIdx.x;
  const int wave = tid >> 6;
  const int lane = tid & 63;
  const int quad = lane >> 4;
  const int n    = lane & 15;

  const int bid     = blockIdx.x;
  const int tile    = bid & 15;
  const int half_id = bid >> 4;
  const int b0      = tile * 16;
  const int hc0     = half_id * 128 + wave * 16;
  const int col_h   = hc0 + n;
  const int col_loc = wave * 16 + n;                  // local col within half

  int* const my_flag = flags + (tile * 2 + half_id) * 16;
  const int* const pa_flag = flags + (tile * 2 + (half_id ^ 1)) * 16;

  __shared__ _Float16 wm_lds[8 * 64 * 8];             // W_mlp B-frags
  __shared__ float    tok_lds[32];                    // [row][e]
  __shared__ __align__(16) _Float16 hl[2][16 * 136];  // local h [par][row][128+8]

  // Build W_mlp fragment LDS (N padded 2->16 with zeros).
  {
    int s8 = tid >> 6, L = tid & 63;
    int nn = L & 15, kq = L >> 4;
    h8 v;
#pragma unroll
    for (int j = 0; j < 8; ++j) {
      int k = s8 * 32 + kq * 8 + j;
      v[j] = (nn < 2) ? WmlpT[nn * 256 + k] : (_Float16)0.f;
    }
    *reinterpret_cast<h8*>(&wm_lds[(s8 * 64 + L) * 8]) = v;
  }
  // Zero local-h LDS (h_0 = 0), both parities.
  for (int i = tid; i < 2 * 16 * 136; i += 512) hl[0][i] = (_Float16)0.f;

  // Register-resident weight fragments (compiler places in AGPRs).
  h8 W[4][8];
  h8 Wf[4];
  float zb[4], db[4], D0[4], D1[4];
#pragma unroll
  for (int g = 0; g < 4; ++g) {
    int col = g * 256 + col_h;
    const _Float16* wp = rkT + col * 256 + quad * 8;
#pragma unroll
    for (int s8 = 0; s8 < 8; ++s8)
      W[g][s8] = *reinterpret_cast<const h8*>(wp + s8 * 32);
    if (quad == 0) {
      Wf[g] = *reinterpret_cast<const h8*>(WeffT + col * 8);
    } else {
#pragma unroll
      for (int j = 0; j < 8; ++j) Wf[g][j] = (_Float16)0.f;
    }
    zb[g] = zbias[col];
    db[g] = dbias[col];
    D0[g] = Deff[col];
    D1[g] = Deff[1024 + col];
  }
  const float sw  = (n < 2) ? scale_w[n] : 0.f;
  const float sb_ = (n < 2) ? scale_b[n] : 0.f;
  const float bm  = (n < 2) ? b_mlp[n]   : 0.f;

  f4 c_frag = {0.f, 0.f, 0.f, 0.f};

  __syncthreads();

  const int rhalf = half_id ^ 1;
  const int lloc  = half_id * 4;   // frag index base, local K half
  const int lrem  = rhalf * 4;     // frag index base, remote K half
  // remote A-frag base: row = n, k = rhalf*128 + quad*8  (f16 units)
  const int hrow_rd_rem = (tile * 16 + n) * 256 + rhalf * 128 + quad * 8;
  // publish base: row = quad*4 + r, col = col_h (f16 units)
  const int hrow_wr = (tile * 16 + quad * 4) * 256 + col_h;
  const float* prow = pulse + (size_t)(b0 + n) * 1024 * 8;

#define LOAD_REMOTE(rem, parR)                                                \
  {                                                                           \
    const _Float16* rp = hbuf + (parR) * 65536 + hrow_rd_rem;                 \
    rem[0] = ic_load16(rp);                                                   \
    rem[1] = ic_load16(rp + 32);                                              \
    rem[2] = ic_load16(rp + 64);                                              \
    rem[3] = ic_load16(rp + 96);                                              \
  }

#define LOAD_LOCAL(la, parR)                                                  \
  {                                                                           \
    _Pragma("unroll")                                                         \
    for (int s = 0; s < 4; ++s)                                               \
      la[s] = *reinterpret_cast<const h8*>(                                   \
          &hl[parR][n * 136 + quad * 8 + s * 32]);                            \
  }

#define GATES_AND_STORE(parW)                                                 \
  {                                                                           \
    _Float16* hw = hbuf + (parW) * 65536 + hrow_wr;                           \
    _Pragma("unroll")                                                         \
    for (int r = 0; r < 4; ++r) {                                             \
      float iv = sigf(acc[0][r]);                                             \
      float fv = sigf(acc[1][r]);                                             \
      float gv = tanh_f(acc[2][r]);                                           \
      float ov = sigf(acc[3][r]);                                             \
      float cc = fv * c_frag[r] + iv * gv;                                    \
      c_frag[r] = cc;                                                         \
      _Float16 hv = (_Float16)(ov * tanh_f(cc));                              \
      hl[parW][(quad * 4 + r) * 136 + col_loc] = hv;                          \
      unsigned int bits = (unsigned int)__builtin_bit_cast(unsigned short, hv);\
      ic_store_h16(hw + r * 256, bits);                                       \
    }                                                                         \
  }

#define SYNC_STEP(t)                                                          \
  {                                                                           \
    ic_fence_stores();        /* this wave's sc0sc1 h-stores ack'd at IC */   \
    __syncthreads();          /* all waves' stores ack'd */                   \
    if (tid == 0) ic_store_flag(my_flag, (t) + 1);                            \
    while (ic_load_flag(pa_flag) < (t) + 1) { }  /* per-wave poll */          \
  }

  // ---------------- encoder: t = 0..1023 ----------------
  for (int t = 0; t < 1024; ++t) {
    const int parR = t & 1;
    const int parW = parR ^ 1;

    h8 rem[4];
    LOAD_REMOTE(rem, parR)    // in flight; not touched until ic_wait4
    h8 la[4];
    LOAD_LOCAL(la, parR)

    h8 pa;
#pragma unroll
    for (int j = 0; j < 8; ++j) pa[j] = (_Float16)0.f;
    if (quad == 0) {
      const f4* pp = reinterpret_cast<const f4*>(prow + (size_t)t * 8);
      f4 p0 = pp[0], p1 = pp[1];
      pa[0] = (_Float16)p0[0]; pa[1] = (_Float16)p0[1];
      pa[2] = (_Float16)p0[2]; pa[3] = (_Float16)p0[3];
      pa[4] = (_Float16)p1[0]; pa[5] = (_Float16)p1[1];
      pa[6] = (_Float16)p1[2]; pa[7] = (_Float16)p1[3];
    }

    f4 acc[4];
#pragma unroll
    for (int g = 0; g < 4; ++g) {
      acc[g][0] = zb[g]; acc[g][1] = zb[g]; acc[g][2] = zb[g]; acc[g][3] = zb[g];
      acc[g] = __builtin_amdgcn_mfma_f32_16x16x32_f16(pa, Wf[g], acc[g], 0, 0, 0);
    }
    // local-half MFMAs while remote loads are in flight
#pragma unroll
    for (int s = 0; s < 4; ++s) {
#pragma unroll
      for (int g = 0; g < 4; ++g)
        acc[g] = __builtin_amdgcn_mfma_f32_16x16x32_f16(la[s], W[g][lloc + s], acc[g], 0, 0, 0);
    }
    ic_wait4(rem[0], rem[1], rem[2], rem[3]);
#pragma unroll
    for (int s = 0; s < 4; ++s) {
#pragma unroll
      for (int g = 0; g < 4; ++g)
        acc[g] = __builtin_amdgcn_mfma_f32_16x16x32_f16(rem[s], W[g][lrem + s], acc[g], 0, 0, 0);
    }

    GATES_AND_STORE(parW)
    SYNC_STEP(t)
  }

  // ---------------- decoder: 35 steps ----------------
  if (tid < 32) tok_lds[tid] = embed[tid & 1];
  __syncthreads();

  for (int s = 0; s < 35; ++s) {
    const int t = 1024 + s;
    const int parR = t & 1;
    const int parW = parR ^ 1;

    h8 rem[4];
    LOAD_REMOTE(rem, parR)
    h8 la[4];
    LOAD_LOCAL(la, parR)
    ic_wait4(rem[0], rem[1], rem[2], rem[3]);

    h8 ha[8];
#pragma unroll
    for (int q = 0; q < 4; ++q) { ha[lloc + q] = la[q]; ha[lrem + q] = rem[q]; }

    if (s > 0) {
      // pred_{s-1} = h_t @ W_mlp + b_mlp  (wave0 publishes)
      f4 pf; pf[0] = bm; pf[1] = bm; pf[2] = bm; pf[3] = bm;
#pragma unroll
      for (int s8 = 0; s8 < 8; ++s8) {
        h8 wb = *reinterpret_cast<const h8*>(&wm_lds[(s8 * 64 + lane) * 8]);
        pf = __builtin_amdgcn_mfma_f32_16x16x32_f16(ha[s8], wb, pf, 0, 0, 0);
      }
      if (wave == 0 && n < 2) {
#pragma unroll
        for (int r = 0; r < 4; ++r) {
          int row = quad * 4 + r;
          float v = pf[r];
          tok_lds[row * 2 + n] = v;
          if (half_id == 0)
            out[((b0 + row) * 35 + (s - 1)) * 2 + n] = v * sw + sb_;
        }
      }
      __syncthreads();
    }

    float tk0[4], tk1[4];
#pragma unroll
    for (int r = 0; r < 4; ++r) {
      int row = quad * 4 + r;
      tk0[r] = tok_lds[row * 2];
      tk1[r] = tok_lds[row * 2 + 1];
    }
    f4 acc[4];
#pragma unroll
    for (int g = 0; g < 4; ++g) {
#pragma unroll
      for (int r = 0; r < 4; ++r)
        acc[g][r] = db[g] + tk0[r] * D0[g] + tk1[r] * D1[g];
    }
#pragma unroll
    for (int s8 = 0; s8 < 8; ++s8) {
#pragma unroll
      for (int g = 0; g < 4; ++g)
        acc[g] = __builtin_amdgcn_mfma_f32_16x16x32_f16(ha[s8], W[g][s8], acc[g], 0, 0, 0);
    }

    GATES_AND_STORE(parW)
    SYNC_STEP(t)
  }

  // final pred_34 from h_{1059} (parity 1; flag 1059 already confirmed)
  {
    h8 rem[4];
    LOAD_REMOTE(rem, 1)
    h8 la[4];
    LOAD_LOCAL(la, 1)
    ic_wait4(rem[0], rem[1], rem[2], rem[3]);
    h8 ha[8];
#pragma unroll
    for (int q = 0; q < 4; ++q) { ha[lloc + q] = la[q]; ha[lrem + q] = rem[q]; }
    f4 pf; pf[0] = bm; pf[1] = bm; pf[2] = bm; pf[3] = bm;
#pragma unroll
    for (int s8 = 0; s8 < 8; ++s8) {
      h8 wb = *reinterpret_cast<const h8*>(&wm_lds[(s8 * 64 + lane) * 8]);
      pf = __builtin_amdgcn_mfma_f32_16x16x32_f16(ha[s8], wb, pf, 0, 0, 0);
    }
    if (half_id == 0 && wave == 0 && n < 2) {
#pragma unroll
      for (int r = 0; r < 4; ++r) {
        int row = quad * 4 + r;
        out[((b0 + row) * 35 + 34) * 2 + n] = pf[r] * sw + sb_;
      }
    }
  }
#undef LOAD_REMOTE
#undef LOAD_LOCAL
#undef GATES_AND_STORE
#undef SYNC_STEP
}

extern "C" void kernel_launch(void* const* d_in, const int* in_sizes, int n_in,
                              void* d_out, int out_size, void* d_ws, size_t ws_size,
                              hipStream_t stream) {
  const float* pulse    = (const float*)d_in[0];
  const float* bn_gamma = (const float*)d_in[1];
  const float* bn_beta  = (const float*)d_in[2];
  const float* bn_mean  = (const float*)d_in[3];
  const float* bn_var   = (const float*)d_in[4];
  const float* W_pulse  = (const float*)d_in[5];
  const float* b_pulse  = (const float*)d_in[6];
  const float* lstm_k   = (const float*)d_in[7];
  const float* lstm_rk  = (const float*)d_in[8];
  const float* lstm_b   = (const float*)d_in[9];
  const float* embed    = (const float*)d_in[10];
  const float* W_eis    = (const float*)d_in[11];
  const float* b_eis    = (const float*)d_in[12];
  const float* W_mlp    = (const float*)d_in[13];
  const float* b_mlp    = (const float*)d_in[14];
  const float* scale_w  = (const float*)d_in[15];
  const float* scale_b  = (const float*)d_in[16];

  char* ws = (char*)d_ws;
  int*      flags = (int*)(ws + WS_FLAGS);
  _Float16* hbuf  = (_Float16*)(ws + WS_HBUF);
  _Float16* rkT   = (_Float16*)(ws + WS_RKT);
  _Float16* WeffT = (_Float16*)(ws + WS_WEFF);
  _Float16* WmlpT = (_Float16*)(ws + WS_WMLP);
  float*    Deff  = (float*)(ws + WS_DEFF);
  float*    zbias = (float*)(ws + WS_ZB);
  float*    dbias = (float*)(ws + WS_DB);

  // zero flags + h double-buffer: (2048 + 262144)/4 = 66048 words
  zero_ws_k<<<258, 256, 0, stream>>>((uint32_t*)d_ws, 66048);
  precompute_k<<<1024, 256, 0, stream>>>(bn_gamma, bn_beta, bn_mean, bn_var,
                                         W_pulse, b_pulse, lstm_k, lstm_rk, lstm_b,
                                         W_eis, b_eis, W_mlp,
                                         rkT, WeffT, WmlpT, Deff, zbias, dbias);
  lstm_main_k<<<32, 512, 0, stream>>>(pulse, embed, b_mlp, scale_w, scale_b,
                                      rkT, WeffT, WmlpT, Deff, zbias, dbias,
                                      hbuf, flags, (float*)d_out);
}